// Round 1
// baseline (291.635 us; speedup 1.0000x reference)
//
#include <hip/hip_runtime.h>
#include <hip/hip_bf16.h>

#define B_ 8
#define C_ 64
#define N_ 4096
#define K_ 20
#define T_ 3
#define O_ 64
#define P_ 20
#define NK_ (N_ * K_) /* 81920 */
#define BN_EPS 1e-5f

// workspace layout (float offsets)
#define WS_FEATT 0                          // B*N*C      = 2,097,152
#define WS_WT (WS_FEATT + B_ * N_ * C_)     // K*T*C*O    =   245,760
#define WS_TAY (WS_WT + K_ * T_ * C_ * O_)  // B*T*N*K    = 1,966,080
#define WS_RAW (WS_TAY + B_ * T_ * NK_)     // B*O*N      = 2,097,152
#define WS_PART (WS_RAW + B_ * O_ * N_)     // 512*64*2   =    65,536
#define WS_STATS (WS_PART + 512 * O_ * 2)   // 128

// K0: feat[b][c][n] -> featT[b][n][c]  (LDS tiled transpose, coalesced both sides)
__global__ void k_transpose_feat(const float* __restrict__ feat, float* __restrict__ featT) {
    __shared__ float t[64][65];
    int b = blockIdx.y;
    int n0 = blockIdx.x * 64;
    int lx = threadIdx.x & 63, ly = threadIdx.x >> 6;  // 256 threads
    const float* fp = feat + b * C_ * N_;
#pragma unroll
    for (int cc = 0; cc < 16; ++cc) {
        int c = ly * 16 + cc;
        t[c][lx] = fp[c * N_ + n0 + lx];
    }
    __syncthreads();
    float* op = featT + (b * N_ + n0) * C_;
#pragma unroll
    for (int u = 0; u < 16; ++u) {
        int n = ly * 16 + u;
        op[n * C_ + lx] = t[lx][n];
    }
}

// K5: conv_w[o][(c*3+t)*20+k] -> Wt[k][t][c][o]
__global__ void k_transpose_w(const float* __restrict__ cw, float* __restrict__ Wt) {
    int tid = blockIdx.x * 256 + threadIdx.x;  // ((k*3+t)*64+c)*64+o
    int o = tid & 63;
    int c = (tid >> 6) & 63;
    int kt = tid >> 12;
    int t = kt % 3, k = kt / 3;
    Wt[tid] = cw[o * (C_ * T_ * K_) + (c * T_ + t) * K_ + k];
}

// K1: taylor. thread = b*NK + n*20+k  -> all weights reads perfectly coalesced.
__global__ void k_taylor(const float* __restrict__ W5, const float* __restrict__ gpc,
                         float* __restrict__ tay) {
    int tid = blockIdx.x * 256 + threadIdx.x;
    int b = tid / NK_;
    int nk = tid - b * NK_;
    const float X = gpc[b * 3 * NK_ + nk];
    const float Y = gpc[b * 3 * NK_ + NK_ + nk];
    const float Z = gpc[b * 3 * NK_ + 2 * NK_ + nk];
    float XX = X * X, YY = Y * Y, ZZ = Z * Z;
    float XY = X * Y, XZ = X * Z, YZ = Y * Z;
    float terms[20];
    terms[0] = 1.f; terms[1] = X;      terms[2] = Y;       terms[3] = Z;
    terms[4] = XX;  terms[5] = YY;     terms[6] = ZZ;
    terms[7] = XX * X; terms[8] = YY * Y; terms[9] = ZZ * Z;
    terms[10] = XY; terms[11] = XZ;    terms[12] = YZ;
    terms[13] = X * XY;  // X^2 Y
    terms[14] = X * XZ;  // X^2 Z
    terms[15] = Y * YZ;  // Y^2 Z
    terms[16] = Y * XY;  // X Y^2
    terms[17] = Z * XZ;  // X Z^2
    terms[18] = Z * YZ;  // Y Z^2
    terms[19] = XY * Z;  // XYZ
    float a0 = 0.f, a1 = 0.f, a2 = 0.f;
    const float* wp = W5 + (size_t)b * P_ * T_ * NK_ + nk;
#pragma unroll
    for (int p = 0; p < P_; ++p) {
        float tp = terms[p];
        a0 += wp[0] * tp;
        a1 += wp[NK_] * tp;
        a2 += wp[2 * NK_] * tp;
        wp += 3 * NK_;
    }
    float* tp = tay + (size_t)b * T_ * NK_ + nk;
    tp[0] = a0;
    tp[NK_] = a1;
    tp[2 * NK_] = a2;
}

// K2: main contraction. Block = (b, 64-n tile), 256 thr = 4 waves splitting c 16-each.
// out[64o][64n] += sum_{k,t,c} Wt[k][t][c][o] * featT[b][idx][c] * tay[b][t][n][k]
__global__ __launch_bounds__(256) void k_main(const float* __restrict__ featT,
                                              const float* __restrict__ Wt,
                                              const float* __restrict__ tay,
                                              const int* __restrict__ idx,
                                              float* __restrict__ raw,
                                              float* __restrict__ part) {
    __shared__ float sW[64][68];  // [c][o], pad 68 -> 2-way max conflicts
    __shared__ float sG[64][68];  // [c][n]
    __shared__ float sT[3][64];   // [t][n]

    const int bid = blockIdx.x;
    const int b = bid >> 6;
    const int n0 = (bid & 63) << 6;
    const int tid = threadIdx.x;
    const int lane = tid & 63;
    const int wv = tid >> 6;
    const int r = lane >> 3;  // o-block: o = r*8 + i
    const int q = lane & 7;   // n-block: n = q*8 + j
    const int nn = tid & 63;  // staging n
    const int cseg = tid >> 6;

    float acc[8][8];
#pragma unroll
    for (int i = 0; i < 8; ++i)
#pragma unroll
        for (int j = 0; j < 8; ++j) acc[i][j] = 0.f;

    const int idx_base = (b * N_ + n0 + nn) * K_;
    const float* featTb = featT + (size_t)b * N_ * C_;

    for (int k = 0; k < K_; ++k) {
        __syncthreads();
        if (tid < 192) {  // stage tay slice
            int t = tid >> 6, n = tid & 63;
            sT[t][n] = tay[((b * T_ + t) * N_ + n0 + n) * K_ + k];
        }
        {  // gather: featT row (256B contiguous) -> column nn of sG
            int m = idx[idx_base + k];
            const float4* src = (const float4*)(featTb + m * C_ + cseg * 16);
            float4 v0 = src[0], v1 = src[1], v2 = src[2], v3 = src[3];
            int cb = cseg * 16;
            sG[cb + 0][nn] = v0.x;  sG[cb + 1][nn] = v0.y;
            sG[cb + 2][nn] = v0.z;  sG[cb + 3][nn] = v0.w;
            sG[cb + 4][nn] = v1.x;  sG[cb + 5][nn] = v1.y;
            sG[cb + 6][nn] = v1.z;  sG[cb + 7][nn] = v1.w;
            sG[cb + 8][nn] = v2.x;  sG[cb + 9][nn] = v2.y;
            sG[cb + 10][nn] = v2.z; sG[cb + 11][nn] = v2.w;
            sG[cb + 12][nn] = v3.x; sG[cb + 13][nn] = v3.y;
            sG[cb + 14][nn] = v3.z; sG[cb + 15][nn] = v3.w;
        }
        __syncthreads();
        for (int t = 0; t < T_; ++t) {
            {  // stage Wt[k][t] (16KB) into sW[c][o] -- coalesced float4
                const float4* src = (const float4*)(Wt + (k * T_ + t) * (C_ * O_) + tid * 16);
                float4 v0 = src[0], v1 = src[1], v2 = src[2], v3 = src[3];
                int e = tid * 16;
                float4* dst = (float4*)&sW[e >> 6][e & 63];
                dst[0] = v0; dst[1] = v1; dst[2] = v2; dst[3] = v3;
            }
            __syncthreads();
            float tj[8];
#pragma unroll
            for (int j = 0; j < 8; ++j) tj[j] = sT[t][q * 8 + j];
            const int cc0 = wv * 16;
#pragma unroll 4
            for (int cc = cc0; cc < cc0 + 16; ++cc) {
                float4 a0 = *(const float4*)&sW[cc][r * 8];
                float4 a1 = *(const float4*)&sW[cc][r * 8 + 4];
                float4 g0 = *(const float4*)&sG[cc][q * 8];
                float4 g1 = *(const float4*)&sG[cc][q * 8 + 4];
                float av[8] = {a0.x, a0.y, a0.z, a0.w, a1.x, a1.y, a1.z, a1.w};
                float bv[8] = {g0.x * tj[0], g0.y * tj[1], g0.z * tj[2], g0.w * tj[3],
                               g1.x * tj[4], g1.y * tj[5], g1.z * tj[6], g1.w * tj[7]};
#pragma unroll
                for (int i = 0; i < 8; ++i)
#pragma unroll
                    for (int j = 0; j < 8; ++j) acc[i][j] += av[i] * bv[j];
            }
            __syncthreads();
        }
    }

    // serialized cross-wave reduction into sW (deterministic)
#pragma unroll 1
    for (int ww = 0; ww < 4; ++ww) {
        if (wv == ww) {
#pragma unroll
            for (int i = 0; i < 8; ++i)
#pragma unroll
                for (int j = 0; j < 8; ++j) {
                    if (ww == 0)
                        sW[r * 8 + i][q * 8 + j] = acc[i][j];
                    else
                        sW[r * 8 + i][q * 8 + j] += acc[i][j];
                }
        }
        __syncthreads();
    }

    {  // write raw tile, coalesced float4
        int o = tid >> 2, seg = tid & 3;
        float4* dst = (float4*)(raw + ((b * O_ + o) * N_) + n0 + seg * 16);
        const float* srow = &sW[o][seg * 16];
        dst[0] = *(const float4*)&srow[0];
        dst[1] = *(const float4*)&srow[4];
        dst[2] = *(const float4*)&srow[8];
        dst[3] = *(const float4*)&srow[12];
    }
    if (tid < 64) {  // per-block BN partial sums
        float s1 = 0.f, s2 = 0.f;
#pragma unroll 8
        for (int n = 0; n < 64; ++n) {
            float v = sW[tid][n];
            s1 += v;
            s2 += v * v;
        }
        part[(bid * 64 + tid) * 2 + 0] = s1;
        part[(bid * 64 + tid) * 2 + 1] = s2;
    }
}

// K3: reduce 512 block-partials per channel -> scale/shift (deterministic)
__global__ void k_bnstats(const float* __restrict__ part, const float* __restrict__ gamma,
                          const float* __restrict__ beta, float* __restrict__ stats) {
    int o = blockIdx.x;
    int tid = threadIdx.x;
    __shared__ float s1s[256], s2s[256];
    float s1 = 0.f, s2 = 0.f;
    for (int j = tid; j < 512; j += 256) {
        s1 += part[(j * 64 + o) * 2 + 0];
        s2 += part[(j * 64 + o) * 2 + 1];
    }
    s1s[tid] = s1;
    s2s[tid] = s2;
    __syncthreads();
    for (int s = 128; s > 0; s >>= 1) {
        if (tid < s) {
            s1s[tid] += s1s[tid + s];
            s2s[tid] += s2s[tid + s];
        }
        __syncthreads();
    }
    if (tid == 0) {
        const float cnt = (float)(B_ * N_);
        float mean = s1s[0] / cnt;
        float var = s2s[0] / cnt - mean * mean;
        float sc = gamma[o] * rsqrtf(var + BN_EPS);
        stats[o * 2 + 0] = sc;
        stats[o * 2 + 1] = beta[o] - mean * sc;
    }
}

// K4: normalize + ReLU, float4
__global__ void k_finalize(const float* __restrict__ raw, const float* __restrict__ stats,
                           float* __restrict__ out) {
    int e = (blockIdx.x * 256 + threadIdx.x) * 4;
    int o = (e >> 12) & 63;
    float sc = stats[o * 2 + 0], sh = stats[o * 2 + 1];
    float4 v = *(const float4*)(raw + e);
    v.x = fmaxf(v.x * sc + sh, 0.f);
    v.y = fmaxf(v.y * sc + sh, 0.f);
    v.z = fmaxf(v.z * sc + sh, 0.f);
    v.w = fmaxf(v.w * sc + sh, 0.f);
    *(float4*)(out + e) = v;
}

extern "C" void kernel_launch(void* const* d_in, const int* in_sizes, int n_in,
                              void* d_out, int out_size, void* d_ws, size_t ws_size,
                              hipStream_t stream) {
    const float* feat = (const float*)d_in[0];
    const int* idx = (const int*)d_in[1];
    const float* gpc = (const float*)d_in[2];
    const float* weights = (const float*)d_in[3];
    const float* conv_w = (const float*)d_in[4];
    const float* gamma = (const float*)d_in[5];
    const float* beta = (const float*)d_in[6];
    float* out = (float*)d_out;
    float* ws = (float*)d_ws;

    float* featT = ws + WS_FEATT;
    float* Wt = ws + WS_WT;
    float* tay = ws + WS_TAY;
    float* raw = ws + WS_RAW;
    float* part = ws + WS_PART;
    float* stats = ws + WS_STATS;

    hipLaunchKernelGGL(k_transpose_feat, dim3(N_ / 64, B_), dim3(256), 0, stream, feat, featT);
    hipLaunchKernelGGL(k_transpose_w, dim3((K_ * T_ * C_ * O_) / 256), dim3(256), 0, stream,
                       conv_w, Wt);
    hipLaunchKernelGGL(k_taylor, dim3(B_ * NK_ / 256), dim3(256), 0, stream, weights, gpc, tay);
    hipLaunchKernelGGL(k_main, dim3(B_ * (N_ / 64)), dim3(256), 0, stream, featT, Wt, tay, idx,
                       raw, part);
    hipLaunchKernelGGL(k_bnstats, dim3(O_), dim3(256), 0, stream, part, gamma, beta, stats);
    hipLaunchKernelGGL(k_finalize, dim3(B_ * O_ * N_ / 4 / 256), dim3(256), 0, stream, raw, stats,
                       out);
}

// Round 2
// 106.969 us; speedup vs baseline: 2.7264x; 2.7264x over previous
//
#include <hip/hip_runtime.h>
#include <hip/hip_bf16.h>

#define B_ 8
#define C_ 64
#define N_ 4096
#define K_ 20
#define T_ 3
#define O_ 64
#define P_ 20
#define NK_ (N_ * K_) /* 81920 */
#define BN_EPS 1e-5f

// workspace layout (float offsets)
#define WS_FEATT 0                            // B*N*C      = 2,097,152
#define WS_WT (WS_FEATT + B_ * N_ * C_)       // 245,760 bf16 -> 122,880 float slots
#define WS_TAY (WS_WT + 122880)               // B*T*N*K    = 1,966,080
#define WS_RAW (WS_TAY + B_ * T_ * NK_)       // B*O*N      = 2,097,152
#define WS_PART (WS_RAW + B_ * O_ * N_)       // 512*64*2   =    65,536
#define WS_STATS (WS_PART + 512 * O_ * 2)     // 128

typedef __attribute__((ext_vector_type(8))) short short8;
typedef __attribute__((ext_vector_type(16))) float f32x16;

__device__ inline unsigned cvtpk_bf16(float lo, float hi) {
    unsigned r;
    asm volatile("v_cvt_pk_bf16_f32 %0, %1, %2" : "=v"(r) : "v"(lo), "v"(hi));
    return r;
}

union U128 {
    uint4 u;
    short8 s;
};
__device__ inline short8 as_short8(uint4 u) {
    U128 x;
    x.u = u;
    return x.s;
}

// K0: feat[b][c][n] -> featT[b][n][c]  (LDS tiled transpose, coalesced both sides)
__global__ void k_transpose_feat(const float* __restrict__ feat, float* __restrict__ featT) {
    __shared__ float t[64][65];
    int b = blockIdx.y;
    int n0 = blockIdx.x * 64;
    int lx = threadIdx.x & 63, ly = threadIdx.x >> 6;  // 256 threads
    const float* fp = feat + b * C_ * N_;
#pragma unroll
    for (int cc = 0; cc < 16; ++cc) {
        int c = ly * 16 + cc;
        t[c][lx] = fp[c * N_ + n0 + lx];
    }
    __syncthreads();
    float* op = featT + (b * N_ + n0) * C_;
#pragma unroll
    for (int u = 0; u < 16; ++u) {
        int n = ly * 16 + u;
        op[n * C_ + lx] = t[lx][n];
    }
}

// K5: pack conv_w into bf16 MFMA A-fragment order.
// frag id = ((k*3+t)*4+cc)*2+oh ; within frag: lane l (o = oh*32+(l&31)),
// 8 bf16 per lane: c = cc*16 + (l>>5)*8 + j
__global__ void k_pack_w(const float* __restrict__ cw, unsigned short* __restrict__ Wf) {
    int e = blockIdx.x * 256 + threadIdx.x;  // 245760 total
    int j = e & 7;
    int l = (e >> 3) & 63;
    int frag = e >> 9;
    int oh = frag & 1;
    int cc = (frag >> 1) & 3;
    int kt = frag >> 3;
    int t = kt % 3, k = kt / 3;
    int o = oh * 32 + (l & 31);
    int c = cc * 16 + (l >> 5) * 8 + j;
    float v = cw[o * (C_ * T_ * K_) + (c * T_ + t) * K_ + k];
    Wf[e] = (unsigned short)(cvtpk_bf16(v, v) & 0xffffu);
}

// K1: taylor. thread = b*NK + n*20+k  -> all weights reads perfectly coalesced.
__global__ void k_taylor(const float* __restrict__ W5, const float* __restrict__ gpc,
                         float* __restrict__ tay) {
    int tid = blockIdx.x * 256 + threadIdx.x;
    int b = tid / NK_;
    int nk = tid - b * NK_;
    const float X = gpc[b * 3 * NK_ + nk];
    const float Y = gpc[b * 3 * NK_ + NK_ + nk];
    const float Z = gpc[b * 3 * NK_ + 2 * NK_ + nk];
    float XX = X * X, YY = Y * Y, ZZ = Z * Z;
    float XY = X * Y, XZ = X * Z, YZ = Y * Z;
    float terms[20];
    terms[0] = 1.f; terms[1] = X;      terms[2] = Y;       terms[3] = Z;
    terms[4] = XX;  terms[5] = YY;     terms[6] = ZZ;
    terms[7] = XX * X; terms[8] = YY * Y; terms[9] = ZZ * Z;
    terms[10] = XY; terms[11] = XZ;    terms[12] = YZ;
    terms[13] = X * XY;
    terms[14] = X * XZ;
    terms[15] = Y * YZ;
    terms[16] = Y * XY;
    terms[17] = Z * XZ;
    terms[18] = Z * YZ;
    terms[19] = XY * Z;
    float a0 = 0.f, a1 = 0.f, a2 = 0.f;
    const float* wp = W5 + (size_t)b * P_ * T_ * NK_ + nk;
#pragma unroll
    for (int p = 0; p < P_; ++p) {
        float tp = terms[p];
        a0 += wp[0] * tp;
        a1 += wp[NK_] * tp;
        a2 += wp[2 * NK_] * tp;
        wp += 3 * NK_;
    }
    float* tp = tay + (size_t)b * T_ * NK_ + nk;
    tp[0] = a0;
    tp[NK_] = a1;
    tp[2 * NK_] = a2;
}

// K2: main contraction via bf16 MFMA 32x32x16.
// Block = (b, 64-n tile), 4 waves; wave wv owns c-slice [wv*16, wv*16+16),
// computes full 64x64 partial with 2x2 register blocking; LDS merge at end.
__global__ __launch_bounds__(256) void k_main(const float* __restrict__ featT,
                                              const unsigned short* __restrict__ Wf,
                                              const float* __restrict__ tay,
                                              const int* __restrict__ idx,
                                              float* __restrict__ raw,
                                              float* __restrict__ part) {
    __shared__ union {
        unsigned short e[3][64][72];  // E[t][n][c] bf16, rows padded to 72
        float out[64][68];            // epilogue merge buffer
    } su;
    __shared__ float sTay[3][K_][64];
    __shared__ int sIdx[K_][64];

    // XCD-aware bijective swizzle (512 blocks, 8 XCDs -> 64-block chunks share b)
    const int bid0 = blockIdx.x;
    const int bid = (bid0 & 7) * 64 + (bid0 >> 3);
    const int b = bid >> 6;
    const int n0 = (bid & 63) << 6;
    const int tid = threadIdx.x;
    const int lane = tid & 63;
    const int wv = tid >> 6;
    const int nl = lane & 31;

    {  // stage idx + tay once (coalesced reads)
        const int* ip = idx + (b * N_ + n0) * K_;
        for (int e = tid; e < 64 * K_; e += 256) sIdx[e % K_][e / K_] = ip[e];
#pragma unroll
        for (int t = 0; t < 3; ++t) {
            const float* tp = tay + ((size_t)(b * 3 + t) * N_ + n0) * K_;
            for (int e = tid; e < 64 * K_; e += 256) sTay[t][e % K_][e / K_] = tp[e];
        }
    }
    __syncthreads();

    f32x16 acc[2][2];
#pragma unroll
    for (int oh = 0; oh < 2; ++oh)
#pragma unroll
        for (int nh = 0; nh < 2; ++nh)
#pragma unroll
            for (int i = 0; i < 16; ++i) acc[oh][nh][i] = 0.f;

    const float* fb = featT + (size_t)b * N_ * C_;

    for (int k = 0; k < K_; ++k) {
        // A-fragments straight from global (L2-resident, coalesced 1KB/wave)
        uint4 araw[3][2];
#pragma unroll
        for (int t = 0; t < 3; ++t)
#pragma unroll
            for (int oh = 0; oh < 2; ++oh)
                araw[t][oh] =
                    *(const uint4*)(Wf + (size_t)((((k * 3 + t) * 4 + wv) * 2 + oh) * 64 + lane) * 8);

        // gather + build E rows (registers only until barrier)
        int m = sIdx[k][lane];
        const float4* src = (const float4*)(fb + m * C_ + wv * 16);
        float4 v0 = src[0], v1 = src[1], v2 = src[2], v3 = src[3];
        float g[16] = {v0.x, v0.y, v0.z, v0.w, v1.x, v1.y, v1.z, v1.w,
                       v2.x, v2.y, v2.z, v2.w, v3.x, v3.y, v3.z, v3.w};
        unsigned pk[3][8];
#pragma unroll
        for (int t = 0; t < 3; ++t) {
            float tv = sTay[t][k][lane];
#pragma unroll
            for (int p = 0; p < 8; ++p) pk[t][p] = cvtpk_bf16(g[2 * p] * tv, g[2 * p + 1] * tv);
        }
        __syncthreads();  // previous iteration's B-reads done
#pragma unroll
        for (int t = 0; t < 3; ++t) {
            *(uint4*)&su.e[t][lane][wv * 16] = make_uint4(pk[t][0], pk[t][1], pk[t][2], pk[t][3]);
            *(uint4*)&su.e[t][lane][wv * 16 + 8] =
                make_uint4(pk[t][4], pk[t][5], pk[t][6], pk[t][7]);
        }
        __syncthreads();  // E ready

        const int kf = lane >> 5;
#pragma unroll
        for (int t = 0; t < 3; ++t) {
            short8 a0 = as_short8(araw[t][0]);
            short8 a1 = as_short8(araw[t][1]);
            uint4 b0r = *(const uint4*)&su.e[t][nl][wv * 16 + kf * 8];
            uint4 b1r = *(const uint4*)&su.e[t][32 + nl][wv * 16 + kf * 8];
            short8 b0 = as_short8(b0r);
            short8 b1 = as_short8(b1r);
            acc[0][0] = __builtin_amdgcn_mfma_f32_32x32x16_bf16(a0, b0, acc[0][0], 0, 0, 0);
            acc[0][1] = __builtin_amdgcn_mfma_f32_32x32x16_bf16(a0, b1, acc[0][1], 0, 0, 0);
            acc[1][0] = __builtin_amdgcn_mfma_f32_32x32x16_bf16(a1, b0, acc[1][0], 0, 0, 0);
            acc[1][1] = __builtin_amdgcn_mfma_f32_32x32x16_bf16(a1, b1, acc[1][1], 0, 0, 0);
        }
    }

    __syncthreads();  // last B-reads done; su.out overlays su.e
    // serialized cross-wave merge (deterministic)
#pragma unroll 1
    for (int ww = 0; ww < 4; ++ww) {
        if (wv == ww) {
#pragma unroll
            for (int oh = 0; oh < 2; ++oh)
#pragma unroll
                for (int nh = 0; nh < 2; ++nh)
#pragma unroll
                    for (int r = 0; r < 16; ++r) {
                        int row = oh * 32 + (r & 3) + ((r >> 2) << 3) + ((lane >> 5) << 2);
                        int col = nh * 32 + nl;
                        if (ww == 0)
                            su.out[row][col] = acc[oh][nh][r];
                        else
                            su.out[row][col] += acc[oh][nh][r];
                    }
        }
        __syncthreads();
    }

    {  // write raw tile, coalesced float4
        int o = tid >> 2, seg = tid & 3;
        float4* dst = (float4*)(raw + ((b * O_ + o) * N_) + n0 + seg * 16);
        const float* srow = &su.out[o][seg * 16];
        dst[0] = *(const float4*)&srow[0];
        dst[1] = *(const float4*)&srow[4];
        dst[2] = *(const float4*)&srow[8];
        dst[3] = *(const float4*)&srow[12];
    }
    if (tid < 64) {  // per-block BN partial sums
        float s1 = 0.f, s2 = 0.f;
#pragma unroll 8
        for (int n = 0; n < 64; ++n) {
            float v = su.out[tid][n];
            s1 += v;
            s2 += v * v;
        }
        part[(bid * 64 + tid) * 2 + 0] = s1;
        part[(bid * 64 + tid) * 2 + 1] = s2;
    }
}

// K3: reduce 512 block-partials per channel -> scale/shift (deterministic)
__global__ void k_bnstats(const float* __restrict__ part, const float* __restrict__ gamma,
                          const float* __restrict__ beta, float* __restrict__ stats) {
    int o = blockIdx.x;
    int tid = threadIdx.x;
    __shared__ float s1s[256], s2s[256];
    float s1 = 0.f, s2 = 0.f;
    for (int j = tid; j < 512; j += 256) {
        s1 += part[(j * 64 + o) * 2 + 0];
        s2 += part[(j * 64 + o) * 2 + 1];
    }
    s1s[tid] = s1;
    s2s[tid] = s2;
    __syncthreads();
    for (int s = 128; s > 0; s >>= 1) {
        if (tid < s) {
            s1s[tid] += s1s[tid + s];
            s2s[tid] += s2s[tid + s];
        }
        __syncthreads();
    }
    if (tid == 0) {
        const float cnt = (float)(B_ * N_);
        float mean = s1s[0] / cnt;
        float var = s2s[0] / cnt - mean * mean;
        float sc = gamma[o] * rsqrtf(var + BN_EPS);
        stats[o * 2 + 0] = sc;
        stats[o * 2 + 1] = beta[o] - mean * sc;
    }
}

// K4: normalize + ReLU, float4
__global__ void k_finalize(const float* __restrict__ raw, const float* __restrict__ stats,
                           float* __restrict__ out) {
    int e = (blockIdx.x * 256 + threadIdx.x) * 4;
    int o = (e >> 12) & 63;
    float sc = stats[o * 2 + 0], sh = stats[o * 2 + 1];
    float4 v = *(const float4*)(raw + e);
    v.x = fmaxf(v.x * sc + sh, 0.f);
    v.y = fmaxf(v.y * sc + sh, 0.f);
    v.z = fmaxf(v.z * sc + sh, 0.f);
    v.w = fmaxf(v.w * sc + sh, 0.f);
    *(float4*)(out + e) = v;
}

extern "C" void kernel_launch(void* const* d_in, const int* in_sizes, int n_in,
                              void* d_out, int out_size, void* d_ws, size_t ws_size,
                              hipStream_t stream) {
    const float* feat = (const float*)d_in[0];
    const int* idx = (const int*)d_in[1];
    const float* gpc = (const float*)d_in[2];
    const float* weights = (const float*)d_in[3];
    const float* conv_w = (const float*)d_in[4];
    const float* gamma = (const float*)d_in[5];
    const float* beta = (const float*)d_in[6];
    float* out = (float*)d_out;
    float* ws = (float*)d_ws;

    float* featT = ws + WS_FEATT;
    unsigned short* Wf = (unsigned short*)(ws + WS_WT);
    float* tay = ws + WS_TAY;
    float* raw = ws + WS_RAW;
    float* part = ws + WS_PART;
    float* stats = ws + WS_STATS;

    hipLaunchKernelGGL(k_transpose_feat, dim3(N_ / 64, B_), dim3(256), 0, stream, feat, featT);
    hipLaunchKernelGGL(k_pack_w, dim3((K_ * T_ * C_ * O_) / 256), dim3(256), 0, stream, conv_w,
                       Wf);
    hipLaunchKernelGGL(k_taylor, dim3(B_ * NK_ / 256), dim3(256), 0, stream, weights, gpc, tay);
    hipLaunchKernelGGL(k_main, dim3(B_ * (N_ / 64)), dim3(256), 0, stream, featT, Wf, tay, idx,
                       raw, part);
    hipLaunchKernelGGL(k_bnstats, dim3(O_), dim3(256), 0, stream, part, gamma, beta, stats);
    hipLaunchKernelGGL(k_finalize, dim3(B_ * O_ * N_ / 4 / 256), dim3(256), 0, stream, raw, stats,
                       out);
}

// Round 3
// 95.663 us; speedup vs baseline: 3.0486x; 1.1182x over previous
//
#include <hip/hip_runtime.h>
#include <hip/hip_bf16.h>

#define B_ 8
#define C_ 64
#define N_ 4096
#define K_ 20
#define T_ 3
#define O_ 64
#define P_ 20
#define NK_ (N_ * K_) /* 81920 */
#define BN_EPS 1e-5f

// workspace layout (float offsets)
#define WS_FEATT 0                            // B*N*C      = 2,097,152
#define WS_WT (WS_FEATT + B_ * N_ * C_)       // 245,760 bf16 -> 122,880 float slots
#define WS_TAY (WS_WT + 122880)               // B*T*N*K    = 1,966,080
#define WS_RAW (WS_TAY + B_ * T_ * NK_)       // B*O*N      = 2,097,152
#define WS_PART (WS_RAW + B_ * O_ * N_)       // 512*64*2   =    65,536
#define WS_STATS (WS_PART + 512 * O_ * 2)     // 128

typedef __attribute__((ext_vector_type(8))) short short8;
typedef __attribute__((ext_vector_type(16))) float f32x16;

__device__ inline unsigned cvtpk_bf16(float lo, float hi) {
    unsigned r;
    asm volatile("v_cvt_pk_bf16_f32 %0, %1, %2" : "=v"(r) : "v"(lo), "v"(hi));
    return r;
}

union U128 {
    uint4 u;
    short8 s;
};
__device__ inline short8 as_short8(uint4 u) {
    U128 x;
    x.u = u;
    return x.s;
}

// K0: feat[b][c][n] -> featT[b][n][c]  (LDS tiled transpose, coalesced both sides)
__global__ void k_transpose_feat(const float* __restrict__ feat, float* __restrict__ featT) {
    __shared__ float t[64][65];
    int b = blockIdx.y;
    int n0 = blockIdx.x * 64;
    int lx = threadIdx.x & 63, ly = threadIdx.x >> 6;  // 256 threads
    const float* fp = feat + b * C_ * N_;
#pragma unroll
    for (int cc = 0; cc < 16; ++cc) {
        int c = ly * 16 + cc;
        t[c][lx] = fp[c * N_ + n0 + lx];
    }
    __syncthreads();
    float* op = featT + (b * N_ + n0) * C_;
#pragma unroll
    for (int u = 0; u < 16; ++u) {
        int n = ly * 16 + u;
        op[n * C_ + lx] = t[lx][n];
    }
}

// K5: pack conv_w into bf16 MFMA A-fragment order.
// frag id = ((k*3+t)*4+cc)*2+oh ; within frag: lane l (o = oh*32+(l&31)),
// 8 bf16 per lane: c = cc*16 + (l>>5)*8 + j
__global__ void k_pack_w(const float* __restrict__ cw, unsigned short* __restrict__ Wf) {
    int e = blockIdx.x * 256 + threadIdx.x;  // 245760 total
    int j = e & 7;
    int l = (e >> 3) & 63;
    int frag = e >> 9;
    int oh = frag & 1;
    int cc = (frag >> 1) & 3;
    int kt = frag >> 3;
    int t = kt % 3, k = kt / 3;
    int o = oh * 32 + (l & 31);
    int c = cc * 16 + (l >> 5) * 8 + j;
    float v = cw[o * (C_ * T_ * K_) + (c * T_ + t) * K_ + k];
    Wf[e] = (unsigned short)(cvtpk_bf16(v, v) & 0xffffu);
}

// K1: taylor. thread = b*NK + n*20+k  -> all weights reads perfectly coalesced.
__global__ void k_taylor(const float* __restrict__ W5, const float* __restrict__ gpc,
                         float* __restrict__ tay) {
    int tid = blockIdx.x * 256 + threadIdx.x;
    int b = tid / NK_;
    int nk = tid - b * NK_;
    const float X = gpc[b * 3 * NK_ + nk];
    const float Y = gpc[b * 3 * NK_ + NK_ + nk];
    const float Z = gpc[b * 3 * NK_ + 2 * NK_ + nk];
    float XX = X * X, YY = Y * Y, ZZ = Z * Z;
    float XY = X * Y, XZ = X * Z, YZ = Y * Z;
    float terms[20];
    terms[0] = 1.f; terms[1] = X;      terms[2] = Y;       terms[3] = Z;
    terms[4] = XX;  terms[5] = YY;     terms[6] = ZZ;
    terms[7] = XX * X; terms[8] = YY * Y; terms[9] = ZZ * Z;
    terms[10] = XY; terms[11] = XZ;    terms[12] = YZ;
    terms[13] = X * XY;
    terms[14] = X * XZ;
    terms[15] = Y * YZ;
    terms[16] = Y * XY;
    terms[17] = Z * XZ;
    terms[18] = Z * YZ;
    terms[19] = XY * Z;
    float a0 = 0.f, a1 = 0.f, a2 = 0.f;
    const float* wp = W5 + (size_t)b * P_ * T_ * NK_ + nk;
#pragma unroll
    for (int p = 0; p < P_; ++p) {
        float tp = terms[p];
        a0 += wp[0] * tp;
        a1 += wp[NK_] * tp;
        a2 += wp[2 * NK_] * tp;
        wp += 3 * NK_;
    }
    float* tp = tay + (size_t)b * T_ * NK_ + nk;
    tp[0] = a0;
    tp[NK_] = a1;
    tp[2 * NK_] = a2;
}

// K2: main contraction via bf16 MFMA 32x32x16, barrier-free inner loop.
// Block = (b, 64-n tile), 4 waves; wave wv owns c-slice [wv*16, wv*16+16).
// Lane builds its own B-fragments directly from gathered featT rows (n is
// lane-local in the MFMA B layout) -> no LDS round-trip, no k-loop barriers.
__global__ __launch_bounds__(256) void k_main(const float* __restrict__ featT,
                                              const unsigned short* __restrict__ Wf,
                                              const float* __restrict__ tay,
                                              const int* __restrict__ idx,
                                              float* __restrict__ raw,
                                              float* __restrict__ part) {
    __shared__ union {
        struct {
            float tayS[3][K_][64];  // 15360 B
            int idxS[K_][64];       //  5120 B
        } s;
        float out[64][68];  // 17408 B epilogue merge buffer
    } su;

    // XCD-aware bijective swizzle (512 blocks, 8 XCDs -> one b per XCD's L2)
    const int bid0 = blockIdx.x;
    const int bid = (bid0 & 7) * 64 + (bid0 >> 3);
    const int b = bid >> 6;
    const int n0 = (bid & 63) << 6;
    const int tid = threadIdx.x;
    const int lane = tid & 63;
    const int wv = tid >> 6;
    const int nl = lane & 31;
    const int kf = lane >> 5;

    {  // stage idx + tay once (coalesced reads)
        const int* ip = idx + (b * N_ + n0) * K_;
        for (int e = tid; e < 64 * K_; e += 256) su.s.idxS[e % K_][e / K_] = ip[e];
#pragma unroll
        for (int t = 0; t < 3; ++t) {
            const float* tp = tay + ((size_t)(b * 3 + t) * N_ + n0) * K_;
            for (int e = tid; e < 64 * K_; e += 256) su.s.tayS[t][e % K_][e / K_] = tp[e];
        }
    }
    __syncthreads();

    f32x16 acc[2][2];
#pragma unroll
    for (int oh = 0; oh < 2; ++oh)
#pragma unroll
        for (int nh = 0; nh < 2; ++nh)
#pragma unroll
            for (int i = 0; i < 16; ++i) acc[oh][nh][i] = 0.f;

    // this lane's c-offset within featT rows
    const float* fb = featT + (size_t)b * N_ * C_ + wv * 16 + kf * 8;

    for (int k = 0; k < K_; ++k) {
        int m0 = su.s.idxS[k][nl];
        int m1 = su.s.idxS[k][nl + 32];
        const float4* s0 = (const float4*)(fb + m0 * C_);
        const float4* s1 = (const float4*)(fb + m1 * C_);
        float4 u0 = s0[0], u1 = s0[1];
        float4 w0 = s1[0], w1 = s1[1];
        float g0[8] = {u0.x, u0.y, u0.z, u0.w, u1.x, u1.y, u1.z, u1.w};
        float g1[8] = {w0.x, w0.y, w0.z, w0.w, w1.x, w1.y, w1.z, w1.w};
#pragma unroll
        for (int t = 0; t < 3; ++t) {
            uint4 a0r = *(const uint4*)(Wf + (size_t)((((k * 3 + t) * 4 + wv) * 2 + 0) * 64 + lane) * 8);
            uint4 a1r = *(const uint4*)(Wf + (size_t)((((k * 3 + t) * 4 + wv) * 2 + 1) * 64 + lane) * 8);
            float tv0 = su.s.tayS[t][k][nl];
            float tv1 = su.s.tayS[t][k][nl + 32];
            unsigned p0[4], p1[4];
#pragma unroll
            for (int p = 0; p < 4; ++p) {
                p0[p] = cvtpk_bf16(g0[2 * p] * tv0, g0[2 * p + 1] * tv0);
                p1[p] = cvtpk_bf16(g1[2 * p] * tv1, g1[2 * p + 1] * tv1);
            }
            short8 bf0 = as_short8(make_uint4(p0[0], p0[1], p0[2], p0[3]));
            short8 bf1 = as_short8(make_uint4(p1[0], p1[1], p1[2], p1[3]));
            short8 a0 = as_short8(a0r);
            short8 a1 = as_short8(a1r);
            acc[0][0] = __builtin_amdgcn_mfma_f32_32x32x16_bf16(a0, bf0, acc[0][0], 0, 0, 0);
            acc[0][1] = __builtin_amdgcn_mfma_f32_32x32x16_bf16(a0, bf1, acc[0][1], 0, 0, 0);
            acc[1][0] = __builtin_amdgcn_mfma_f32_32x32x16_bf16(a1, bf0, acc[1][0], 0, 0, 0);
            acc[1][1] = __builtin_amdgcn_mfma_f32_32x32x16_bf16(a1, bf1, acc[1][1], 0, 0, 0);
        }
    }

    __syncthreads();  // all LDS reads of su.s done; su.out overlays it
    // serialized cross-wave merge (deterministic)
#pragma unroll 1
    for (int ww = 0; ww < 4; ++ww) {
        if (wv == ww) {
#pragma unroll
            for (int oh = 0; oh < 2; ++oh)
#pragma unroll
                for (int nh = 0; nh < 2; ++nh)
#pragma unroll
                    for (int r = 0; r < 16; ++r) {
                        int row = oh * 32 + (r & 3) + ((r >> 2) << 3) + ((lane >> 5) << 2);
                        int col = nh * 32 + nl;
                        if (ww == 0)
                            su.out[row][col] = acc[oh][nh][r];
                        else
                            su.out[row][col] += acc[oh][nh][r];
                    }
        }
        __syncthreads();
    }

    {  // write raw tile, coalesced float4
        int o = tid >> 2, seg = tid & 3;
        float4* dst = (float4*)(raw + ((b * O_ + o) * N_) + n0 + seg * 16);
        const float* srow = &su.out[o][seg * 16];
        dst[0] = *(const float4*)&srow[0];
        dst[1] = *(const float4*)&srow[4];
        dst[2] = *(const float4*)&srow[8];
        dst[3] = *(const float4*)&srow[12];
    }
    if (tid < 64) {  // per-block BN partial sums
        float s1 = 0.f, s2 = 0.f;
#pragma unroll 8
        for (int n = 0; n < 64; ++n) {
            float v = su.out[tid][n];
            s1 += v;
            s2 += v * v;
        }
        part[(bid * 64 + tid) * 2 + 0] = s1;
        part[(bid * 64 + tid) * 2 + 1] = s2;
    }
}

// K3: reduce 512 block-partials per channel -> scale/shift (deterministic)
__global__ void k_bnstats(const float* __restrict__ part, const float* __restrict__ gamma,
                          const float* __restrict__ beta, float* __restrict__ stats) {
    int o = blockIdx.x;
    int tid = threadIdx.x;
    __shared__ float s1s[256], s2s[256];
    float s1 = 0.f, s2 = 0.f;
    for (int j = tid; j < 512; j += 256) {
        s1 += part[(j * 64 + o) * 2 + 0];
        s2 += part[(j * 64 + o) * 2 + 1];
    }
    s1s[tid] = s1;
    s2s[tid] = s2;
    __syncthreads();
    for (int s = 128; s > 0; s >>= 1) {
        if (tid < s) {
            s1s[tid] += s1s[tid + s];
            s2s[tid] += s2s[tid + s];
        }
        __syncthreads();
    }
    if (tid == 0) {
        const float cnt = (float)(B_ * N_);
        float mean = s1s[0] / cnt;
        float var = s2s[0] / cnt - mean * mean;
        float sc = gamma[o] * rsqrtf(var + BN_EPS);
        stats[o * 2 + 0] = sc;
        stats[o * 2 + 1] = beta[o] - mean * sc;
    }
}

// K4: normalize + ReLU, float4
__global__ void k_finalize(const float* __restrict__ raw, const float* __restrict__ stats,
                           float* __restrict__ out) {
    int e = (blockIdx.x * 256 + threadIdx.x) * 4;
    int o = (e >> 12) & 63;
    float sc = stats[o * 2 + 0], sh = stats[o * 2 + 1];
    float4 v = *(const float4*)(raw + e);
    v.x = fmaxf(v.x * sc + sh, 0.f);
    v.y = fmaxf(v.y * sc + sh, 0.f);
    v.z = fmaxf(v.z * sc + sh, 0.f);
    v.w = fmaxf(v.w * sc + sh, 0.f);
    *(float4*)(out + e) = v;
}

extern "C" void kernel_launch(void* const* d_in, const int* in_sizes, int n_in,
                              void* d_out, int out_size, void* d_ws, size_t ws_size,
                              hipStream_t stream) {
    const float* feat = (const float*)d_in[0];
    const int* idx = (const int*)d_in[1];
    const float* gpc = (const float*)d_in[2];
    const float* weights = (const float*)d_in[3];
    const float* conv_w = (const float*)d_in[4];
    const float* gamma = (const float*)d_in[5];
    const float* beta = (const float*)d_in[6];
    float* out = (float*)d_out;
    float* ws = (float*)d_ws;

    float* featT = ws + WS_FEATT;
    unsigned short* Wf = (unsigned short*)(ws + WS_WT);
    float* tay = ws + WS_TAY;
    float* raw = ws + WS_RAW;
    float* part = ws + WS_PART;
    float* stats = ws + WS_STATS;

    hipLaunchKernelGGL(k_transpose_feat, dim3(N_ / 64, B_), dim3(256), 0, stream, feat, featT);
    hipLaunchKernelGGL(k_pack_w, dim3((K_ * T_ * C_ * O_) / 256), dim3(256), 0, stream, conv_w,
                       Wf);
    hipLaunchKernelGGL(k_taylor, dim3(B_ * NK_ / 256), dim3(256), 0, stream, weights, gpc, tay);
    hipLaunchKernelGGL(k_main, dim3(B_ * (N_ / 64)), dim3(256), 0, stream, featT, Wf, tay, idx,
                       raw, part);
    hipLaunchKernelGGL(k_bnstats, dim3(O_), dim3(256), 0, stream, part, gamma, beta, stats);
    hipLaunchKernelGGL(k_finalize, dim3(B_ * O_ * N_ / 4 / 256), dim3(256), 0, stream, raw, stats,
                       out);
}

// Round 4
// 83.646 us; speedup vs baseline: 3.4865x; 1.1437x over previous
//
#include <hip/hip_runtime.h>
#include <hip/hip_bf16.h>

#define B_ 8
#define C_ 64
#define N_ 4096
#define K_ 20
#define T_ 3
#define O_ 64
#define P_ 20
#define NK_ (N_ * K_) /* 81920 */
#define BN_EPS 1e-5f
#define PADW 68

// workspace layout (float offsets)
#define WS_FEATT 0                            // B*N*C      = 2,097,152
#define WS_WT (WS_FEATT + B_ * N_ * C_)       // 245,760 bf16 -> 122,880 float slots
#define WS_TAY (WS_WT + 122880)               // B*T*N*K    = 1,966,080
#define WS_RAW (WS_TAY + B_ * T_ * NK_)       // B*O*N      = 2,097,152
#define WS_PART (WS_RAW + B_ * O_ * N_)       // 512*64*2   =    65,536
#define WS_STATS (WS_PART + 512 * O_ * 2)     // 128

typedef __attribute__((ext_vector_type(8))) short short8;
typedef __attribute__((ext_vector_type(16))) float f32x16;

__device__ inline unsigned cvtpk_bf16(float lo, float hi) {
    unsigned r;
    asm volatile("v_cvt_pk_bf16_f32 %0, %1, %2" : "=v"(r) : "v"(lo), "v"(hi));
    return r;
}

union U128 {
    uint4 u;
    short8 s;
};
__device__ inline short8 as_short8(uint4 u) {
    U128 x;
    x.u = u;
    return x.s;
}

// K0: feat[b][c][n] -> featT[b][n][c]  (LDS tiled transpose, coalesced both sides)
__global__ void k_transpose_feat(const float* __restrict__ feat, float* __restrict__ featT) {
    __shared__ float t[64][65];
    int b = blockIdx.y;
    int n0 = blockIdx.x * 64;
    int lx = threadIdx.x & 63, ly = threadIdx.x >> 6;  // 256 threads
    const float* fp = feat + b * C_ * N_;
#pragma unroll
    for (int cc = 0; cc < 16; ++cc) {
        int c = ly * 16 + cc;
        t[c][lx] = fp[c * N_ + n0 + lx];
    }
    __syncthreads();
    float* op = featT + (b * N_ + n0) * C_;
#pragma unroll
    for (int u = 0; u < 16; ++u) {
        int n = ly * 16 + u;
        op[n * C_ + lx] = t[lx][n];
    }
}

// K5: pack conv_w into bf16 MFMA A-fragment order.
// frag id = ((k*3+t)*4+cc)*2+oh ; within frag: lane l (o = oh*32+(l&31)),
// 8 bf16 per lane: c = cc*16 + (l>>5)*8 + j
__global__ void k_pack_w(const float* __restrict__ cw, unsigned short* __restrict__ Wf) {
    int e = blockIdx.x * 256 + threadIdx.x;  // 245760 total
    int j = e & 7;
    int l = (e >> 3) & 63;
    int frag = e >> 9;
    int oh = frag & 1;
    int cc = (frag >> 1) & 3;
    int kt = frag >> 3;
    int t = kt % 3, k = kt / 3;
    int o = oh * 32 + (l & 31);
    int c = cc * 16 + (l >> 5) * 8 + j;
    float v = cw[o * (C_ * T_ * K_) + (c * T_ + t) * K_ + k];
    Wf[e] = (unsigned short)(cvtpk_bf16(v, v) & 0xffffu);
}

// K1: taylor. thread = b*NK + n*20+k  -> all weights reads perfectly coalesced.
__global__ void k_taylor(const float* __restrict__ W5, const float* __restrict__ gpc,
                         float* __restrict__ tay) {
    int tid = blockIdx.x * 256 + threadIdx.x;
    int b = tid / NK_;
    int nk = tid - b * NK_;
    const float X = gpc[b * 3 * NK_ + nk];
    const float Y = gpc[b * 3 * NK_ + NK_ + nk];
    const float Z = gpc[b * 3 * NK_ + 2 * NK_ + nk];
    float XX = X * X, YY = Y * Y, ZZ = Z * Z;
    float XY = X * Y, XZ = X * Z, YZ = Y * Z;
    float terms[20];
    terms[0] = 1.f; terms[1] = X;      terms[2] = Y;       terms[3] = Z;
    terms[4] = XX;  terms[5] = YY;     terms[6] = ZZ;
    terms[7] = XX * X; terms[8] = YY * Y; terms[9] = ZZ * Z;
    terms[10] = XY; terms[11] = XZ;    terms[12] = YZ;
    terms[13] = X * XY;
    terms[14] = X * XZ;
    terms[15] = Y * YZ;
    terms[16] = Y * XY;
    terms[17] = Z * XZ;
    terms[18] = Z * YZ;
    terms[19] = XY * Z;
    float a0 = 0.f, a1 = 0.f, a2 = 0.f;
    const float* wp = W5 + (size_t)b * P_ * T_ * NK_ + nk;
#pragma unroll
    for (int p = 0; p < P_; ++p) {
        float tp = terms[p];
        a0 += wp[0] * tp;
        a1 += wp[NK_] * tp;
        a2 += wp[2 * NK_] * tp;
        wp += 3 * NK_;
    }
    float* tp = tay + (size_t)b * T_ * NK_ + nk;
    tp[0] = a0;
    tp[NK_] = a1;
    tp[2 * NK_] = a2;
}

// K2: main contraction via bf16 MFMA 32x32x16.
// Block = (b, 64-n tile), 512 threads = 8 waves: wv = (wc = c-slice 0..3, wo = o-half 0..1).
// Gathers staged cooperatively into double-buffered padded LDS; 1 barrier/iter.
__global__ __launch_bounds__(512, 4) void k_main(const float* __restrict__ featT,
                                                 const unsigned short* __restrict__ Wf,
                                                 const float* __restrict__ tay,
                                                 const int* __restrict__ idx,
                                                 float* __restrict__ raw,
                                                 float* __restrict__ part) {
    __shared__ float G[2][64][PADW];  // 34816 B, padded: 2-way max on read & write
    __shared__ union {
        struct {
            float tayS[3][K_][64];  // 15360 B
            int idxS[K_][64];       //  5120 B
        } s;
        float out[64][68];  // 17408 B epilogue merge buffer
    } su;

    // XCD-aware bijective swizzle (512 blocks, 8 XCDs -> one b per XCD's L2)
    const int bid0 = blockIdx.x;
    const int bid = (bid0 & 7) * 64 + (bid0 >> 3);
    const int b = bid >> 6;
    const int n0 = (bid & 63) << 6;
    const int tid = threadIdx.x;
    const int lane = tid & 63;
    const int wv = tid >> 6;  // 0..7
    const int wc = wv & 3;    // c-slice 16*wc
    const int wo = wv >> 2;   // o-half 32*wo
    const int nl = lane & 31;
    const int kf = lane >> 5;

    {  // stage idx + tay once (coalesced reads)
        const int* ip = idx + (b * N_ + n0) * K_;
        for (int e = tid; e < 64 * K_; e += 512) su.s.idxS[e % K_][e / K_] = ip[e];
#pragma unroll
        for (int t = 0; t < 3; ++t) {
            const float* tp = tay + ((size_t)(b * 3 + t) * N_ + n0) * K_;
            for (int e = tid; e < 64 * K_; e += 512) su.s.tayS[t][e % K_][e / K_] = tp[e];
        }
    }
    __syncthreads();

    f32x16 acc[2];
#pragma unroll
    for (int nh = 0; nh < 2; ++nh)
#pragma unroll
        for (int i = 0; i < 16; ++i) acc[nh][i] = 0.f;

    const float* fb = featT + (size_t)b * N_ * C_;
    // staging assignment: thread covers rows r1 = tid>>4 (0..31) and r1+32, seg = tid&15
    const int r1 = tid >> 4, r2 = r1 + 32, sseg = tid & 15;

    // prologue: load k=0 gather data into regs (16-lane contiguous 256B runs)
    float4 st1 = *(const float4*)(fb + su.s.idxS[0][r1] * C_ + sseg * 4);
    float4 st2 = *(const float4*)(fb + su.s.idxS[0][r2] * C_ + sseg * 4);

    for (int k = 0; k < K_; ++k) {
        float* Gb = &G[k & 1][0][0];
        *(float4*)(Gb + r1 * PADW + sseg * 4) = st1;
        *(float4*)(Gb + r2 * PADW + sseg * 4) = st2;
        __syncthreads();  // G[k&1] published; G[(k+1)&1] readers (iter k-1) already done
        if (k + 1 < K_) {  // issue next gather; flies under this iter's compute
            st1 = *(const float4*)(fb + su.s.idxS[k + 1][r1] * C_ + sseg * 4);
            st2 = *(const float4*)(fb + su.s.idxS[k + 1][r2] * C_ + sseg * 4);
        }
        // this lane's two B-rows (8 floats each), 2-way-max LDS reads
        const float* row0 = Gb + nl * PADW + wc * 16 + kf * 8;
        const float* row1 = Gb + (nl + 32) * PADW + wc * 16 + kf * 8;
        float4 u0 = *(const float4*)row0, u1 = *(const float4*)(row0 + 4);
        float4 w0 = *(const float4*)row1, w1 = *(const float4*)(row1 + 4);
        float g0[8] = {u0.x, u0.y, u0.z, u0.w, u1.x, u1.y, u1.z, u1.w};
        float g1[8] = {w0.x, w0.y, w0.z, w0.w, w1.x, w1.y, w1.z, w1.w};
#pragma unroll
        for (int t = 0; t < 3; ++t) {
            uint4 ar = *(const uint4*)(Wf +
                                       (size_t)((((k * 3 + t) * 4 + wc) * 2 + wo) * 64 + lane) * 8);
            float tv0 = su.s.tayS[t][k][nl];
            float tv1 = su.s.tayS[t][k][nl + 32];
            unsigned p0[4], p1[4];
#pragma unroll
            for (int p = 0; p < 4; ++p) {
                p0[p] = cvtpk_bf16(g0[2 * p] * tv0, g0[2 * p + 1] * tv0);
                p1[p] = cvtpk_bf16(g1[2 * p] * tv1, g1[2 * p + 1] * tv1);
            }
            short8 bf0 = as_short8(make_uint4(p0[0], p0[1], p0[2], p0[3]));
            short8 bf1 = as_short8(make_uint4(p1[0], p1[1], p1[2], p1[3]));
            short8 a0 = as_short8(ar);
            acc[0] = __builtin_amdgcn_mfma_f32_32x32x16_bf16(a0, bf0, acc[0], 0, 0, 0);
            acc[1] = __builtin_amdgcn_mfma_f32_32x32x16_bf16(a0, bf1, acc[1], 0, 0, 0);
        }
    }

    __syncthreads();  // all LDS reads of su.s done; su.out overlays it
    // serialized cross-wave c-merge (deterministic); the two wo halves are disjoint rows
#pragma unroll 1
    for (int ww = 0; ww < 4; ++ww) {
        if (wc == ww) {
#pragma unroll
            for (int nh = 0; nh < 2; ++nh)
#pragma unroll
                for (int r = 0; r < 16; ++r) {
                    int row = wo * 32 + (r & 3) + ((r >> 2) << 3) + (kf << 2);
                    int col = nh * 32 + nl;
                    if (ww == 0)
                        su.out[row][col] = acc[nh][r];
                    else
                        su.out[row][col] += acc[nh][r];
                }
        }
        __syncthreads();
    }

    if (tid < 256) {  // write raw tile, coalesced float4
        int o = tid >> 2, seg = tid & 3;
        float4* dst = (float4*)(raw + ((b * O_ + o) * N_) + n0 + seg * 16);
        const float* srow = &su.out[o][seg * 16];
        dst[0] = *(const float4*)&srow[0];
        dst[1] = *(const float4*)&srow[4];
        dst[2] = *(const float4*)&srow[8];
        dst[3] = *(const float4*)&srow[12];
    }
    if (tid < 64) {  // per-block BN partial sums
        float s1 = 0.f, s2 = 0.f;
#pragma unroll 8
        for (int n = 0; n < 64; ++n) {
            float v = su.out[tid][n];
            s1 += v;
            s2 += v * v;
        }
        part[(bid * 64 + tid) * 2 + 0] = s1;
        part[(bid * 64 + tid) * 2 + 1] = s2;
    }
}

// K3: reduce 512 block-partials per channel -> scale/shift (deterministic)
__global__ void k_bnstats(const float* __restrict__ part, const float* __restrict__ gamma,
                          const float* __restrict__ beta, float* __restrict__ stats) {
    int o = blockIdx.x;
    int tid = threadIdx.x;
    __shared__ float s1s[256], s2s[256];
    float s1 = 0.f, s2 = 0.f;
    for (int j = tid; j < 512; j += 256) {
        s1 += part[(j * 64 + o) * 2 + 0];
        s2 += part[(j * 64 + o) * 2 + 1];
    }
    s1s[tid] = s1;
    s2s[tid] = s2;
    __syncthreads();
    for (int s = 128; s > 0; s >>= 1) {
        if (tid < s) {
            s1s[tid] += s1s[tid + s];
            s2s[tid] += s2s[tid + s];
        }
        __syncthreads();
    }
    if (tid == 0) {
        const float cnt = (float)(B_ * N_);
        float mean = s1s[0] / cnt;
        float var = s2s[0] / cnt - mean * mean;
        float sc = gamma[o] * rsqrtf(var + BN_EPS);
        stats[o * 2 + 0] = sc;
        stats[o * 2 + 1] = beta[o] - mean * sc;
    }
}

// K4: normalize + ReLU, float4
__global__ void k_finalize(const float* __restrict__ raw, const float* __restrict__ stats,
                           float* __restrict__ out) {
    int e = (blockIdx.x * 256 + threadIdx.x) * 4;
    int o = (e >> 12) & 63;
    float sc = stats[o * 2 + 0], sh = stats[o * 2 + 1];
    float4 v = *(const float4*)(raw + e);
    v.x = fmaxf(v.x * sc + sh, 0.f);
    v.y = fmaxf(v.y * sc + sh, 0.f);
    v.z = fmaxf(v.z * sc + sh, 0.f);
    v.w = fmaxf(v.w * sc + sh, 0.f);
    *(float4*)(out + e) = v;
}

extern "C" void kernel_launch(void* const* d_in, const int* in_sizes, int n_in,
                              void* d_out, int out_size, void* d_ws, size_t ws_size,
                              hipStream_t stream) {
    const float* feat = (const float*)d_in[0];
    const int* idx = (const int*)d_in[1];
    const float* gpc = (const float*)d_in[2];
    const float* weights = (const float*)d_in[3];
    const float* conv_w = (const float*)d_in[4];
    const float* gamma = (const float*)d_in[5];
    const float* beta = (const float*)d_in[6];
    float* out = (float*)d_out;
    float* ws = (float*)d_ws;

    float* featT = ws + WS_FEATT;
    unsigned short* Wf = (unsigned short*)(ws + WS_WT);
    float* tay = ws + WS_TAY;
    float* raw = ws + WS_RAW;
    float* part = ws + WS_PART;
    float* stats = ws + WS_STATS;

    hipLaunchKernelGGL(k_transpose_feat, dim3(N_ / 64, B_), dim3(256), 0, stream, feat, featT);
    hipLaunchKernelGGL(k_pack_w, dim3((K_ * T_ * C_ * O_) / 256), dim3(256), 0, stream, conv_w,
                       Wf);
    hipLaunchKernelGGL(k_taylor, dim3(B_ * NK_ / 256), dim3(256), 0, stream, weights, gpc, tay);
    hipLaunchKernelGGL(k_main, dim3(B_ * (N_ / 64)), dim3(512), 0, stream, featT, Wf, tay, idx,
                       raw, part);
    hipLaunchKernelGGL(k_bnstats, dim3(O_), dim3(256), 0, stream, part, gamma, beta, stats);
    hipLaunchKernelGGL(k_finalize, dim3(B_ * O_ * N_ / 4 / 256), dim3(256), 0, stream, raw, stats,
                       out);
}